// Round 7
// baseline (442.926 us; speedup 1.0000x reference)
//
#include <hip/hip_runtime.h>

#define B_ 4
#define S_ 4096
#define D_ 1024
#define H_ 16
#define DH 64
#define CHUNK 64
#define NC (S_ / CHUNK)   // 64 chunks
#define BH (B_ * H_)      // 64 (b,h) sequences
#define EPS 1e-6f

typedef __bf16 bf16;
typedef __bf16 bf16x8 __attribute__((ext_vector_type(8)));
typedef float v4f __attribute__((ext_vector_type(4)));

#define MFMA16(a, b, c) __builtin_amdgcn_mfma_f32_16x16x32_bf16(a, b, c, 0, 0, 0)

// async global->LDS, 16B per lane; LDS dest = wave-uniform base + lane*16
__device__ __forceinline__ void load_lds16(const bf16* g, bf16* l) {
  __builtin_amdgcn_global_load_lds(
      (const __attribute__((address_space(1))) unsigned int*)g,
      (__attribute__((address_space(3))) unsigned int*)l, 16, 0, 0);
}

// XOR-swizzled element offset for [R][72] bf16 LDS tiles (R<=64).
// (row,col) -> row*72 + ((col>>3 ^ row>>3)&7)*8 + (col&7).  Bijection; keeps
// 8-elem groups contiguous (b128-safe); kills transpose-scatter conflicts.
__device__ __forceinline__ int swz72(int row, int col) {
  return row * 72 + ((((col >> 3) ^ (row >> 3)) & 7) << 3) + (col & 7);
}

// ---------------------------------------------------------------------------
// fp32 -> bf16 convert (x): 8 elems/thread, vectorized.
// ---------------------------------------------------------------------------
__global__ __launch_bounds__(256) void cvt_f32_bf16(const float* __restrict__ in,
                                                    bf16* __restrict__ out) {
  const size_t i = ((size_t)blockIdx.x * 256 + threadIdx.x) * 8;
  float4 a = *(const float4*)(in + i);
  float4 b = *(const float4*)(in + i + 4);
  bf16x8 o;
  o[0] = (bf16)a.x; o[1] = (bf16)a.y; o[2] = (bf16)a.z; o[3] = (bf16)a.w;
  o[4] = (bf16)b.x; o[5] = (bf16)b.y; o[6] = (bf16)b.z; o[7] = (bf16)b.w;
  *(bf16x8*)(out + i) = o;
}

// ---------------------------------------------------------------------------
// Fused weight transpose + fp32->bf16 for all 4 weights (z selects matrix).
// ---------------------------------------------------------------------------
__global__ __launch_bounds__(256) void transpose_w4(
    const float* __restrict__ w0, const float* __restrict__ w1,
    const float* __restrict__ w2, const float* __restrict__ w3,
    bf16* __restrict__ out) {
  __shared__ float tile[32][33];
  const int z = blockIdx.z;
  const float* in = (z == 0) ? w0 : (z == 1) ? w1 : (z == 2) ? w2 : w3;
  bf16* o = out + (size_t)z * D_ * D_;
  const int bx = blockIdx.x * 32, by = blockIdx.y * 32;
  const int tx = threadIdx.x & 31, ty = threadIdx.x >> 5;  // 32 x 8
#pragma unroll
  for (int i = 0; i < 32; i += 8)
    tile[ty + i][tx] = in[(size_t)(by + ty + i) * D_ + bx + tx];
  __syncthreads();
#pragma unroll
  for (int i = 0; i < 32; i += 8)
    o[(size_t)(bx + ty + i) * D_ + by + tx] = (bf16)tile[tx][ty + i];
}

// ---------------------------------------------------------------------------
// NT GEMM, double-buffered global_load_lds prefetch, SWIZZLED LDS staging.
// (Round-0 proven kernel — unchanged.)
// ---------------------------------------------------------------------------
__global__ __launch_bounds__(256) void gemm_nt(const bf16* __restrict__ A,
                                               const bf16* __restrict__ BT,
                                               bf16* __restrict__ o0,
                                               bf16* __restrict__ o1,
                                               bf16* __restrict__ o2,
                                               float* __restrict__ of) {
  constexpr int TM = 128, BK = 32;
  constexpr int CLD = 132;
  __shared__ __align__(16) char smem[32768];
  float* Cl = (float*)smem;

  const int tid = threadIdx.x;
  const int wave = tid >> 6, lane = tid & 63;
  const int quad = lane >> 4, l16 = lane & 15;
  const int bm = blockIdx.x * TM;
  const int zz = blockIdx.y >> 3;
  const int colg = (blockIdx.y & 7) * 128;
  const int wm = (wave & 1) * 64, wn = (wave >> 1) * 64;
  const int act = (of == nullptr) && (zz < 2);
  bf16* ob = (zz == 0) ? o0 : (zz == 1) ? o1 : o2;

  const int srow = wave * 16 + (lane >> 2);
  const int sgrp = ((lane & 3) - ((lane >> 2) >> 1)) & 3;
  const bf16* gA0 = A + (size_t)(bm + srow) * D_ + sgrp * 8;
  const bf16* gA1 = gA0 + (size_t)64 * D_;
  const bf16* gB0 = BT + ((size_t)blockIdx.y * 128 + srow) * D_ + sgrp * 8;
  const bf16* gB1 = gB0 + (size_t)64 * D_;

  int offA[4], offB[4];
#pragma unroll
  for (int i = 0; i < 4; i++) {
    const int pg = (quad + (l16 >> 1)) & 3;
    offA[i] = (wm + i * 16 + l16) * BK + pg * 8;
    offB[i] = (wn + i * 16 + l16) * BK + pg * 8;
  }

  v4f zero = {0.f, 0.f, 0.f, 0.f};
  v4f acc[4][4];
#pragma unroll
  for (int i = 0; i < 4; i++)
#pragma unroll
    for (int j = 0; j < 4; j++) acc[i][j] = zero;

  auto stage = [&](int ks, int s) {
    bf16* As = (bf16*)(smem + s * 16384);
    bf16* Bs = As + 4096;
    const int ko = ks * BK;
    load_lds16(gA0 + ko, As + wave * 16 * BK);
    load_lds16(gA1 + ko, As + (64 + wave * 16) * BK);
    load_lds16(gB0 + ko, Bs + wave * 16 * BK);
    load_lds16(gB1 + ko, Bs + (64 + wave * 16) * BK);
  };
  auto compute = [&](int s) {
    const bf16* As = (const bf16*)(smem + s * 16384);
    const bf16* Bs = As + 4096;
    bf16x8 af[4], bfr[4];
#pragma unroll
    for (int i = 0; i < 4; i++) af[i] = *(const bf16x8*)&As[offA[i]];
#pragma unroll
    for (int j = 0; j < 4; j++) bfr[j] = *(const bf16x8*)&Bs[offB[j]];
#pragma unroll
    for (int i = 0; i < 4; i++)
#pragma unroll
      for (int j = 0; j < 4; j++) acc[i][j] = MFMA16(af[i], bfr[j], acc[i][j]);
  };

  constexpr int NK = D_ / BK;  // 32
  stage(0, 0);
  __syncthreads();
  for (int k = 0; k < NK; k += 2) {
    if (k + 1 < NK) stage(k + 1, 1);
    compute(0);
    __syncthreads();
    if (k + 2 < NK) stage(k + 2, 0);
    compute(1);
    __syncthreads();
  }

  const int lr = (wave & 1) * 16 + quad * 4;
  const int rrow = tid >> 3;
  const int rseg = (tid & 7) * 16;
  const int grow = bm + (rrow >> 4) * 64 + (rrow & 15);
#pragma unroll
  for (int i = 0; i < 4; i++) {
    __syncthreads();
#pragma unroll
    for (int j = 0; j < 4; j++) {
      const int col = wn + j * 16 + l16;
#pragma unroll
      for (int r = 0; r < 4; r++) {
        float x = acc[i][j][r];
        if (act) x = x > 0.f ? x + 1.f : __expf(x);
        Cl[(lr + r) * CLD + col] = x;
      }
    }
    __syncthreads();
    const float* src = &Cl[rrow * CLD + rseg];
    if (of) {
      float* dst = of + (size_t)(grow + i * 16) * D_ + colg + rseg;
#pragma unroll
      for (int u = 0; u < 4; u++)
        *(float4*)(dst + u * 4) = *(const float4*)(src + u * 4);
    } else {
      bf16x8 q0, q1;
#pragma unroll
      for (int u = 0; u < 8; u++) { q0[u] = (bf16)src[u]; q1[u] = (bf16)src[8 + u]; }
      bf16* dst = ob + (size_t)(grow + i * 16) * D_ + colg + rseg;
      *(bf16x8*)dst = q0;
      *(bf16x8*)(dst + 8) = q1;
    }
  }
}

// ---------------------------------------------------------------------------
// FUSED sequential scan: replaces chunk_kv + state_prefix + attn_pass2.
// Grid: 256 blocks x 256 thr.  bid -> (bh, es): 4 e-slice siblings per bh,
// clustered on one XCD (same bid%8) so duplicated Q/K reads share L2.
// Per block: carry S[d=0..63][e-slice 16] as ONE v4f/wave (fp32, exact) and
// z[64] in LDS across the 64 chunks; per chunk:
//   P1: issue c+1 loads; S0T<-S_frag; P=mask(QK^T); Pl,denl
//   P2: den += q.z; nacc = P@V + Q@S0
//   P3: S += K^T@V; z += colsum K; Ol <- nacc/den; stage c+1 to LDS
//   (P1 of c+1): coalesced Ol -> global
// MFMA operand patterns copied from the proven attn_pass2 / chunk_kv.
// ---------------------------------------------------------------------------
__global__ __launch_bounds__(256) void fused_scan(
    const bf16* __restrict__ qb, const bf16* __restrict__ kb,
    const bf16* __restrict__ vb, const float* __restrict__ sc,
    bf16* __restrict__ ao) {
  __shared__ __align__(16) bf16 Ql[2][CHUNK * 72];
  __shared__ __align__(16) bf16 Kl[2][CHUNK * 72];
  __shared__ __align__(16) bf16 KT[2][CHUNK * 72];  // KT[d][t] swizzled
  __shared__ __align__(16) bf16 VT[2][16 * 72];     // VT[e_loc][t] swizzled
  __shared__ __align__(16) bf16 S0T[16 * 72];       // S0T[e_loc][d] swizzled
  __shared__ __align__(16) bf16 Pl[CHUNK * 72];     // masked P swizzled
  __shared__ __align__(16) bf16 Ol[CHUNK * 72];     // out staging swizzled
  __shared__ float zl[DH];
  __shared__ float denl[CHUNK];

  const int tid = threadIdx.x;
  const int wave = tid >> 6, lane = tid & 63;
  const int quad = lane >> 4, l16 = lane & 15;
  // XCD-clustered mapping: all 4 es-siblings of a bh share bid%8.
  const int r8 = blockIdx.x & 7, q8 = blockIdx.x >> 3;
  const int bh = r8 * 8 + (q8 >> 2), es = q8 & 3;
  const int b = bh >> 4, h = bh & 15;

  // ---- init state ----
  const float* scb = sc + (size_t)bh * (DH + 1) * DH;
  v4f S_frag;  // S[d = wave*16+quad*4+r][e = es*16+l16], fp32
#pragma unroll
  for (int r = 0; r < 4; r++)
    S_frag[r] = scb[(wave * 16 + quad * 4 + r) * 64 + es * 16 + l16];
  if (tid < DH) zl[tid] = scb[4096 + tid];

  // staging roles
  const int sr = tid >> 3, sg = (tid & 7) * 8;   // Q/K rows sr, sr+32
  const int vrow = tid >> 1, ve8 = (tid & 1) * 8;  // V/out rows (tid<128)
  const size_t seqbase = ((size_t)(b * S_)) * D_ + h * DH;

  // ---- prologue: stage chunk 0 into buffer 0 ----
  {
    bf16x8 rq0 = *(const bf16x8*)(qb + seqbase + (size_t)sr * D_ + sg);
    bf16x8 rq1 = *(const bf16x8*)(qb + seqbase + (size_t)(sr + 32) * D_ + sg);
    bf16x8 rk0 = *(const bf16x8*)(kb + seqbase + (size_t)sr * D_ + sg);
    bf16x8 rk1 = *(const bf16x8*)(kb + seqbase + (size_t)(sr + 32) * D_ + sg);
    *(bf16x8*)&Ql[0][sr * 72 + sg] = rq0;
    *(bf16x8*)&Ql[0][(sr + 32) * 72 + sg] = rq1;
    *(bf16x8*)&Kl[0][sr * 72 + sg] = rk0;
    *(bf16x8*)&Kl[0][(sr + 32) * 72 + sg] = rk1;
#pragma unroll
    for (int u = 0; u < 8; u++) {
      KT[0][swz72(sg + u, sr)] = rk0[u];
      KT[0][swz72(sg + u, sr + 32)] = rk1[u];
    }
    if (tid < 128) {
      bf16x8 rv = *(const bf16x8*)(vb + seqbase + (size_t)vrow * D_ + es * 16 + ve8);
#pragma unroll
      for (int u = 0; u < 8; u++) VT[0][swz72(ve8 + u, vrow)] = rv[u];
    }
  }
  __syncthreads();

  const v4f zero = {0.f, 0.f, 0.f, 0.f};
#pragma unroll 2
  for (int c = 0; c < NC; c++) {
    const int cur = c & 1, nxt = cur ^ 1;
    const size_t cb = seqbase + (size_t)(c * 64) * D_;
    const bool more = (c + 1 < NC);

    // ---- P1 ----
    // issue next-chunk loads early (used in P3's stage-write)
    bf16x8 rq0 = {}, rq1 = {}, rk0 = {}, rk1 = {}, rv = {};
    if (more) {
      const size_t nb = cb + (size_t)64 * D_;
      rq0 = *(const bf16x8*)(qb + nb + (size_t)sr * D_ + sg);
      rq1 = *(const bf16x8*)(qb + nb + (size_t)(sr + 32) * D_ + sg);
      rk0 = *(const bf16x8*)(kb + nb + (size_t)sr * D_ + sg);
      rk1 = *(const bf16x8*)(kb + nb + (size_t)(sr + 32) * D_ + sg);
      if (tid < 128)
        rv = *(const bf16x8*)(vb + nb + (size_t)vrow * D_ + es * 16 + ve8);
    }
    // deferred output store for chunk c-1 (Ol written P3(c-1), barrier since)
    if (c > 0 && tid < 128) {
      bf16x8 o8 = *(const bf16x8*)&Ol[swz72(vrow, ve8)];
      *(bf16x8*)(ao + cb - (size_t)64 * D_ + (size_t)vrow * D_ + es * 16 + ve8) = o8;
    }
    // S0T <- S_frag (bf16 operand for Q@S0)
#pragma unroll
    for (int r = 0; r < 4; r++)
      S0T[swz72(l16, wave * 16 + quad * 4 + r)] = (bf16)S_frag[r];
    // P = Q K^T (masked incl. diagonal)
    bf16x8 aq[2];
    v4f pacc[4];
#pragma unroll
    for (int j = 0; j < 4; j++) pacc[j] = zero;
#pragma unroll
    for (int ks = 0; ks < 2; ks++) {
      aq[ks] = *(const bf16x8*)&Ql[cur][(wave * 16 + l16) * 72 + ks * 32 + quad * 8];
#pragma unroll
      for (int j = 0; j < 4; j++) {
        bf16x8 bk = *(const bf16x8*)&Kl[cur][(j * 16 + l16) * 72 + ks * 32 + quad * 8];
        pacc[j] = MFMA16(aq[ks], bk, pacc[j]);
      }
    }
    float rs[4] = {0.f, 0.f, 0.f, 0.f};
#pragma unroll
    for (int j = 0; j < 4; j++)
#pragma unroll
      for (int r = 0; r < 4; r++) {
        int t = wave * 16 + quad * 4 + r;
        int col = j * 16 + l16;
        float p = (col <= t) ? pacc[j][r] : 0.f;
        Pl[swz72(t, col)] = (bf16)p;
        rs[r] += p;
      }
#pragma unroll
    for (int m = 1; m < 16; m <<= 1)
#pragma unroll
      for (int r = 0; r < 4; r++) rs[r] += __shfl_xor(rs[r], m, 64);
    if (l16 == 0)
#pragma unroll
      for (int r = 0; r < 4; r++) denl[wave * 16 + quad * 4 + r] = rs[r];
    __syncthreads();

    // ---- P2 ----
    // den += q . z0 (z not yet updated with this chunk)
    {
      const int t = tid >> 2, p = tid & 3;
      bf16x8 qa = *(const bf16x8*)&Ql[cur][t * 72 + p * 16];
      bf16x8 qb2 = *(const bf16x8*)&Ql[cur][t * 72 + p * 16 + 8];
      float qz = 0.f;
#pragma unroll
      for (int u = 0; u < 8; u++)
        qz += (float)qa[u] * zl[p * 16 + u] + (float)qb2[u] * zl[p * 16 + 8 + u];
      qz += __shfl_xor(qz, 1, 64);
      qz += __shfl_xor(qz, 2, 64);
      if (p == 0) denl[t] += qz;
    }
    // num = P@V + Q@S0  (out: 64 t x 16 e-slice -> one v4f)
    v4f nacc = zero;
    bf16x8 bvv[2];
#pragma unroll
    for (int ks = 0; ks < 2; ks++) {
      bvv[ks] = *(const bf16x8*)&VT[cur][swz72(l16, ks * 32 + quad * 8)];
      bf16x8 ap = *(const bf16x8*)&Pl[swz72(wave * 16 + l16, ks * 32 + quad * 8)];
      nacc = MFMA16(ap, bvv[ks], nacc);
    }
#pragma unroll
    for (int ks = 0; ks < 2; ks++) {
      bf16x8 bs = *(const bf16x8*)&S0T[swz72(l16, ks * 32 + quad * 8)];
      nacc = MFMA16(aq[ks], bs, nacc);
    }
    __syncthreads();

    // ---- P3 ----
    // S += K^T @ V (chunk_kv pattern; VT frags reused from P2)
#pragma unroll
    for (int ks = 0; ks < 2; ks++) {
      bf16x8 ak = *(const bf16x8*)&KT[cur][swz72(wave * 16 + l16, ks * 32 + quad * 8)];
      S_frag = MFMA16(ak, bvv[ks], S_frag);
    }
    // z += colsum K
    {
      const int d = tid >> 2, p = tid & 3;
      bf16x8 a0 = *(const bf16x8*)&KT[cur][swz72(d, p * 16)];
      bf16x8 a1 = *(const bf16x8*)&KT[cur][swz72(d, p * 16 + 8)];
      float zp = 0.f;
#pragma unroll
      for (int u = 0; u < 8; u++) zp += (float)a0[u] + (float)a1[u];
      zp += __shfl_xor(zp, 1, 64);
      zp += __shfl_xor(zp, 2, 64);
      if (p == 0) zl[d] += zp;
    }
    // out staging (den ready since P2 barrier)
#pragma unroll
    for (int r = 0; r < 4; r++) {
      int t = wave * 16 + quad * 4 + r;
      Ol[swz72(t, l16)] = (bf16)(nacc[r] / (denl[t] + EPS));
    }
    // stage chunk c+1 into nxt buffers (compiler waits the early loads here)
    if (more) {
      *(bf16x8*)&Ql[nxt][sr * 72 + sg] = rq0;
      *(bf16x8*)&Ql[nxt][(sr + 32) * 72 + sg] = rq1;
      *(bf16x8*)&Kl[nxt][sr * 72 + sg] = rk0;
      *(bf16x8*)&Kl[nxt][(sr + 32) * 72 + sg] = rk1;
#pragma unroll
      for (int u = 0; u < 8; u++) {
        KT[nxt][swz72(sg + u, sr)] = rk0[u];
        KT[nxt][swz72(sg + u, sr + 32)] = rk1[u];
      }
      if (tid < 128)
#pragma unroll
        for (int u = 0; u < 8; u++) VT[nxt][swz72(ve8 + u, vrow)] = rv[u];
    }
    __syncthreads();
  }
  // final chunk's output
  if (tid < 128) {
    const size_t cb = seqbase + (size_t)((NC - 1) * 64) * D_;
    bf16x8 o8 = *(const bf16x8*)&Ol[swz72(vrow, ve8)];
    *(bf16x8*)(ao + cb + (size_t)vrow * D_ + es * 16 + ve8) = o8;
  }
}

// ---------------------------------------------------------------------------
extern "C" void kernel_launch(void* const* d_in, const int* in_sizes, int n_in,
                              void* d_out, int out_size, void* d_ws, size_t ws_size,
                              hipStream_t stream) {
  const float* x  = (const float*)d_in[0];
  const float* sc = (const float*)d_in[1];
  const float* Wq = (const float*)d_in[2];
  const float* Wk = (const float*)d_in[3];
  const float* Wv = (const float*)d_in[4];
  const float* Wo = (const float*)d_in[5];
  float* out = (float*)d_out;

  const size_t MSZ = (size_t)B_ * S_ * D_;  // 16,777,216 elems
  const size_t WSZ = (size_t)D_ * D_;       // 1,048,576 elems
  bf16* xb = (bf16*)d_ws;
  bf16* qb = xb + MSZ;
  bf16* kb = qb + MSZ;
  bf16* vb = kb + MSZ;
  bf16* ao = vb + MSZ;
  bf16* wt = ao + MSZ;  // 4 transposed bf16 weight matrices [q|k|v|o]

  cvt_f32_bf16<<<MSZ / (256 * 8), 256, 0, stream>>>(x, xb);
  transpose_w4<<<dim3(32, 32, 4), 256, 0, stream>>>(Wq, Wk, Wv, Wo, wt);

  // fused QKV GEMM: BT rows 0..3071 span wt[q|k|v]
  gemm_nt<<<dim3(128, 24), 256, 0, stream>>>(xb, wt, qb, kb, vb, nullptr);

  // fused chunk-scan attention (replaces chunk_kv + state_prefix + attn_pass2)
  fused_scan<<<256, 256, 0, stream>>>(qb, kb, vb, sc, ao);

  gemm_nt<<<dim3(128, 8), 256, 0, stream>>>(ao, wt + 3 * WSZ, nullptr, nullptr,
                                            nullptr, out);
}

// Round 8
// 394.929 us; speedup vs baseline: 1.1215x; 1.1215x over previous
//
#include <hip/hip_runtime.h>

#define B_ 4
#define S_ 4096
#define D_ 1024
#define H_ 16
#define DH 64
#define CHUNK 64
#define NC (S_ / CHUNK)   // 64 chunks
#define BH (B_ * H_)      // 64 (b,h) sequences
#define EPS 1e-6f

typedef __bf16 bf16;
typedef __bf16 bf16x8 __attribute__((ext_vector_type(8)));
typedef float v4f __attribute__((ext_vector_type(4)));

#define MFMA16(a, b, c) __builtin_amdgcn_mfma_f32_16x16x32_bf16(a, b, c, 0, 0, 0)

// async global->LDS, 16B per lane; LDS dest = wave-uniform base + lane*16
__device__ __forceinline__ void load_lds16(const bf16* g, bf16* l) {
  __builtin_amdgcn_global_load_lds(
      (const __attribute__((address_space(1))) unsigned int*)g,
      (__attribute__((address_space(3))) unsigned int*)l, 16, 0, 0);
}

// XOR-swizzled element offset for [R][72] bf16 LDS tiles (R<=64).
// (row,col) -> row*72 + ((col>>3 ^ row>>3)&7)*8 + (col&7).  Bijection; keeps
// 8-elem groups contiguous (b128-safe); kills transpose-scatter conflicts.
__device__ __forceinline__ int swz72(int row, int col) {
  return row * 72 + ((((col >> 3) ^ (row >> 3)) & 7) << 3) + (col & 7);
}

// ---------------------------------------------------------------------------
// fp32 -> bf16 convert (x): 8 elems/thread, vectorized.
// ---------------------------------------------------------------------------
__global__ __launch_bounds__(256) void cvt_f32_bf16(const float* __restrict__ in,
                                                    bf16* __restrict__ out) {
  const size_t i = ((size_t)blockIdx.x * 256 + threadIdx.x) * 8;
  float4 a = *(const float4*)(in + i);
  float4 b = *(const float4*)(in + i + 4);
  bf16x8 o;
  o[0] = (bf16)a.x; o[1] = (bf16)a.y; o[2] = (bf16)a.z; o[3] = (bf16)a.w;
  o[4] = (bf16)b.x; o[5] = (bf16)b.y; o[6] = (bf16)b.z; o[7] = (bf16)b.w;
  *(bf16x8*)(out + i) = o;
}

// ---------------------------------------------------------------------------
// Fused weight transpose + fp32->bf16 for all 4 weights (z selects matrix).
// ---------------------------------------------------------------------------
__global__ __launch_bounds__(256) void transpose_w4(
    const float* __restrict__ w0, const float* __restrict__ w1,
    const float* __restrict__ w2, const float* __restrict__ w3,
    bf16* __restrict__ out) {
  __shared__ float tile[32][33];
  const int z = blockIdx.z;
  const float* in = (z == 0) ? w0 : (z == 1) ? w1 : (z == 2) ? w2 : w3;
  bf16* o = out + (size_t)z * D_ * D_;
  const int bx = blockIdx.x * 32, by = blockIdx.y * 32;
  const int tx = threadIdx.x & 31, ty = threadIdx.x >> 5;  // 32 x 8
#pragma unroll
  for (int i = 0; i < 32; i += 8)
    tile[ty + i][tx] = in[(size_t)(by + ty + i) * D_ + bx + tx];
  __syncthreads();
#pragma unroll
  for (int i = 0; i < 32; i += 8)
    o[(size_t)(bx + ty + i) * D_ + by + tx] = (bf16)tile[tx][ty + i];
}

// ---------------------------------------------------------------------------
// NT GEMM, double-buffered global_load_lds prefetch, SWIZZLED LDS staging.
// (Round-0 proven kernel — unchanged.  256x256 8-phase variant: spilled, do
// not retry.  Fused middle scan: regressed (occupancy), do not retry.)
// ---------------------------------------------------------------------------
__global__ __launch_bounds__(256) void gemm_nt(const bf16* __restrict__ A,
                                               const bf16* __restrict__ BT,
                                               bf16* __restrict__ o0,
                                               bf16* __restrict__ o1,
                                               bf16* __restrict__ o2,
                                               float* __restrict__ of) {
  constexpr int TM = 128, BK = 32;
  constexpr int CLD = 132;
  __shared__ __align__(16) char smem[32768];
  float* Cl = (float*)smem;

  const int tid = threadIdx.x;
  const int wave = tid >> 6, lane = tid & 63;
  const int quad = lane >> 4, l16 = lane & 15;
  const int bm = blockIdx.x * TM;
  const int zz = blockIdx.y >> 3;
  const int colg = (blockIdx.y & 7) * 128;
  const int wm = (wave & 1) * 64, wn = (wave >> 1) * 64;
  const int act = (of == nullptr) && (zz < 2);
  bf16* ob = (zz == 0) ? o0 : (zz == 1) ? o1 : o2;

  const int srow = wave * 16 + (lane >> 2);
  const int sgrp = ((lane & 3) - ((lane >> 2) >> 1)) & 3;
  const bf16* gA0 = A + (size_t)(bm + srow) * D_ + sgrp * 8;
  const bf16* gA1 = gA0 + (size_t)64 * D_;
  const bf16* gB0 = BT + ((size_t)blockIdx.y * 128 + srow) * D_ + sgrp * 8;
  const bf16* gB1 = gB0 + (size_t)64 * D_;

  int offA[4], offB[4];
#pragma unroll
  for (int i = 0; i < 4; i++) {
    const int pg = (quad + (l16 >> 1)) & 3;
    offA[i] = (wm + i * 16 + l16) * BK + pg * 8;
    offB[i] = (wn + i * 16 + l16) * BK + pg * 8;
  }

  v4f zero = {0.f, 0.f, 0.f, 0.f};
  v4f acc[4][4];
#pragma unroll
  for (int i = 0; i < 4; i++)
#pragma unroll
    for (int j = 0; j < 4; j++) acc[i][j] = zero;

  auto stage = [&](int ks, int s) {
    bf16* As = (bf16*)(smem + s * 16384);
    bf16* Bs = As + 4096;
    const int ko = ks * BK;
    load_lds16(gA0 + ko, As + wave * 16 * BK);
    load_lds16(gA1 + ko, As + (64 + wave * 16) * BK);
    load_lds16(gB0 + ko, Bs + wave * 16 * BK);
    load_lds16(gB1 + ko, Bs + (64 + wave * 16) * BK);
  };
  auto compute = [&](int s) {
    const bf16* As = (const bf16*)(smem + s * 16384);
    const bf16* Bs = As + 4096;
    bf16x8 af[4], bfr[4];
#pragma unroll
    for (int i = 0; i < 4; i++) af[i] = *(const bf16x8*)&As[offA[i]];
#pragma unroll
    for (int j = 0; j < 4; j++) bfr[j] = *(const bf16x8*)&Bs[offB[j]];
#pragma unroll
    for (int i = 0; i < 4; i++)
#pragma unroll
      for (int j = 0; j < 4; j++) acc[i][j] = MFMA16(af[i], bfr[j], acc[i][j]);
  };

  constexpr int NK = D_ / BK;  // 32
  stage(0, 0);
  __syncthreads();
  for (int k = 0; k < NK; k += 2) {
    if (k + 1 < NK) stage(k + 1, 1);
    compute(0);
    __syncthreads();
    if (k + 2 < NK) stage(k + 2, 0);
    compute(1);
    __syncthreads();
  }

  const int lr = (wave & 1) * 16 + quad * 4;
  const int rrow = tid >> 3;
  const int rseg = (tid & 7) * 16;
  const int grow = bm + (rrow >> 4) * 64 + (rrow & 15);
#pragma unroll
  for (int i = 0; i < 4; i++) {
    __syncthreads();
#pragma unroll
    for (int j = 0; j < 4; j++) {
      const int col = wn + j * 16 + l16;
#pragma unroll
      for (int r = 0; r < 4; r++) {
        float x = acc[i][j][r];
        if (act) x = x > 0.f ? x + 1.f : __expf(x);
        Cl[(lr + r) * CLD + col] = x;
      }
    }
    __syncthreads();
    const float* src = &Cl[rrow * CLD + rseg];
    if (of) {
      float* dst = of + (size_t)(grow + i * 16) * D_ + colg + rseg;
#pragma unroll
      for (int u = 0; u < 4; u++)
        *(float4*)(dst + u * 4) = *(const float4*)(src + u * 4);
    } else {
      bf16x8 q0, q1;
#pragma unroll
      for (int u = 0; u < 8; u++) { q0[u] = (bf16)src[u]; q1[u] = (bf16)src[8 + u]; }
      bf16* dst = ob + (size_t)(grow + i * 16) * D_ + colg + rseg;
      *(bf16x8*)dst = q0;
      *(bf16x8*)(dst + 8) = q1;
    }
  }
}

// ---------------------------------------------------------------------------
// Pass 1: per-chunk KV outer-product sums (bf16 out) + k-sums (fp32), MFMA.
// KT/VT staged transposed with swz72.  grid (NC, BH) x 256.
// ---------------------------------------------------------------------------
__global__ __launch_bounds__(256) void chunk_kv(const bf16* __restrict__ kb,
                                                const bf16* __restrict__ vb,
                                                bf16* __restrict__ csum,
                                                float* __restrict__ zbuf) {
  __shared__ __align__(16) bf16 KT[DH * 72];  // KT[d][t] (swizzled)
  __shared__ __align__(16) bf16 VT[DH * 72];  // VT[e][t] (swizzled)
  const int tid = threadIdx.x;
  const int wave = tid >> 6, lane = tid & 63;
  const int quad = lane >> 4, l16 = lane & 15;
  const int c = blockIdx.x, bh = blockIdx.y;
  const int b = bh >> 4, h = bh & 15;
  const size_t gbase = ((size_t)(b * S_ + c * CHUNK)) * D_ + h * DH;
#pragma unroll
  for (int rep = 0; rep < 2; rep++) {
    int flat = tid + rep * 256;
    int r = flat >> 3, sg = (flat & 7) * 8;  // r = t, sg = d0
    bf16x8 kk = *(const bf16x8*)(kb + gbase + (size_t)r * D_ + sg);
    bf16x8 vv = *(const bf16x8*)(vb + gbase + (size_t)r * D_ + sg);
#pragma unroll
    for (int u = 0; u < 8; u++) {
      KT[swz72(sg + u, r)] = kk[u];
      VT[swz72(sg + u, r)] = vv[u];
    }
  }
  __syncthreads();

  v4f zero = {0.f, 0.f, 0.f, 0.f};
  v4f acc[4];
#pragma unroll
  for (int j = 0; j < 4; j++) acc[j] = zero;
#pragma unroll
  for (int ks = 0; ks < 2; ks++) {
    bf16x8 ak = *(const bf16x8*)&KT[swz72(wave * 16 + l16, ks * 32 + quad * 8)];
#pragma unroll
    for (int j = 0; j < 4; j++) {
      bf16x8 bv = *(const bf16x8*)&VT[swz72(j * 16 + l16, ks * 32 + quad * 8)];
      acc[j] = MFMA16(ak, bv, acc[j]);
    }
  }
  bf16* out = csum + ((size_t)bh * NC + c) * 4096;
#pragma unroll
  for (int j = 0; j < 4; j++)
#pragma unroll
    for (int r = 0; r < 4; r++)
      out[(wave * 16 + quad * 4 + r) * 64 + (j * 16 + l16)] = (bf16)acc[j][r];

  // z[d] = sum_t K[t][d]: 4 lanes per d, 16 elems each, shfl reduce (fp32)
  {
    const int d = tid >> 2, p = tid & 3;
    bf16x8 a0 = *(const bf16x8*)&KT[swz72(d, p * 16)];
    bf16x8 a1 = *(const bf16x8*)&KT[swz72(d, p * 16 + 8)];
    float zp = 0.f;
#pragma unroll
    for (int u = 0; u < 8; u++) zp += (float)a0[u] + (float)a1[u];
    zp += __shfl_xor(zp, 1, 64);
    zp += __shfl_xor(zp, 2, 64);
    if (p == 0) zbuf[((size_t)bh * NC + c) * 64 + d] = zp;
  }
}

// ---------------------------------------------------------------------------
// Exclusive prefix over chunks + state_cache init — PARALLEL SCAN.
// grid (BH, 65) x 256.  y<64: block owns (bh, 64-elem x-group): loads all 64
// chunks of its group in one coalesced burst (8KB), scans in LDS/registers
// (thread = one x, 16 chunks serial; 4-wave tree via partial[]), writes bf16
// exclusive prefix in one burst.  No dependent HBM chain (the old version
// walked 64 chunks serially through HBM at ~700 cyc/step).
// y==64: z-part (fp32, tiny) — serial walk, 64 threads.
// ---------------------------------------------------------------------------
__global__ __launch_bounds__(256) void state_prefix(const float* __restrict__ sc,
                                                    const bf16* __restrict__ csum,
                                                    float* __restrict__ zbuf,
                                                    bf16* __restrict__ stb) {
  const int bh = blockIdx.x;
  const int g = blockIdx.y;
  const int tid = threadIdx.x;
  const float* scb = sc + (size_t)bh * (DH + 1) * DH;
  if (g == 64) {
    if (tid < DH) {
      const int d = tid;
      float run = scb[4096 + d];
      float* p = zbuf + (size_t)bh * NC * 64 + d;
#pragma unroll 1
      for (int c = 0; c < NC; c += 4) {
        float t0 = p[(size_t)(c + 0) * 64];
        float t1 = p[(size_t)(c + 1) * 64];
        float t2 = p[(size_t)(c + 2) * 64];
        float t3 = p[(size_t)(c + 3) * 64];
        p[(size_t)(c + 0) * 64] = run; run += t0;
        p[(size_t)(c + 1) * 64] = run; run += t1;
        p[(size_t)(c + 2) * 64] = run; run += t2;
        p[(size_t)(c + 3) * 64] = run; run += t3;
      }
    }
    return;
  }
  __shared__ bf16 tile[NC][64];   // [c][x_loc] 8KB
  __shared__ bf16 otile[NC][64];  // output staging 8KB
  __shared__ float partial[4][64];
  const int x0 = g * 64;
  const bf16* base = csum + (size_t)bh * NC * 4096 + x0;
#pragma unroll
  for (int rep = 0; rep < 2; rep++) {
    int flat = tid + rep * 256;
    int c = flat >> 3, seg = (flat & 7) * 8;
    *(bf16x8*)&tile[c][seg] = *(const bf16x8*)(base + (size_t)c * 4096 + seg);
  }
  __syncthreads();
  const int x = tid & 63, cq = tid >> 6, c0 = cq * 16;
  float v[16];
  float s = 0.f;
#pragma unroll
  for (int k = 0; k < 16; k++) { v[k] = (float)tile[c0 + k][x]; s += v[k]; }
  partial[cq][x] = s;
  __syncthreads();
  float run = scb[x0 + x];
#pragma unroll
  for (int q = 0; q < 3; q++)
    if (q < cq) run += partial[q][x];
#pragma unroll
  for (int k = 0; k < 16; k++) { otile[c0 + k][x] = (bf16)run; run += v[k]; }
  __syncthreads();
  bf16* obase = stb + (size_t)bh * NC * 4096 + x0;
#pragma unroll
  for (int rep = 0; rep < 2; rep++) {
    int flat = tid + rep * 256;
    int c = flat >> 3, seg = (flat & 7) * 8;
    *(bf16x8*)(obase + (size_t)c * 4096 + seg) = *(const bf16x8*)&otile[c][seg];
  }
}

// ---------------------------------------------------------------------------
// Pass 2: P = mask(Q K^T) (incl. diagonal), num = P@V + Q@S0,
// den = rowsum(P) + Q.z0, out = num/(den+eps).  grid (NC, BH) x 256 (4 waves).
// swz72-swizzled tiles; output routed through Ql for coalesced 16B stores.
// (Round-6 proven version — unchanged.)
// ---------------------------------------------------------------------------
__global__ __launch_bounds__(256) void attn_pass2(
    const bf16* __restrict__ qb, const bf16* __restrict__ kb,
    const bf16* __restrict__ vb, const float* __restrict__ zbuf,
    const bf16* __restrict__ stb, bf16* __restrict__ ao) {
  __shared__ __align__(16) bf16 Ql[CHUNK * 72];
  __shared__ __align__(16) bf16 Kl[CHUNK * 72];
  __shared__ __align__(16) bf16 VT[DH * 72];    // VT[e][j] = V[j][e]
  __shared__ __align__(16) bf16 S0T[DH * 72];   // S0T[e][d] = S0[d][e]
  __shared__ __align__(16) bf16 Pl[CHUNK * 72]; // masked P [t][j]
  __shared__ float denl[CHUNK];
  __shared__ float z0l[DH];
  const int tid = threadIdx.x;
  const int wave = tid >> 6, lane = tid & 63;
  const int quad = lane >> 4, l16 = lane & 15;
  const int c = blockIdx.x, bh = blockIdx.y;
  const int b = bh >> 4, h = bh & 15;
  const size_t gbase = ((size_t)(b * S_ + c * CHUNK)) * D_ + h * DH;

#pragma unroll
  for (int rep = 0; rep < 2; rep++) {
    int flat = tid + rep * 256;
    int r = flat >> 3, sg = (flat & 7) * 8;
    *(bf16x8*)&Ql[swz72(r, sg)] = *(const bf16x8*)(qb + gbase + (size_t)r * D_ + sg);
    *(bf16x8*)&Kl[swz72(r, sg)] = *(const bf16x8*)(kb + gbase + (size_t)r * D_ + sg);
    bf16x8 vv = *(const bf16x8*)(vb + gbase + (size_t)r * D_ + sg);
#pragma unroll
    for (int u = 0; u < 8; u++) VT[swz72(sg + u, r)] = vv[u];
  }
  // S0 staging from bf16 prefix states: thread handles 16 contiguous elems
  {
    const bf16* stb_c = stb + ((size_t)bh * NC + c) * 4096;
    const int f0 = tid * 16;
    const int col = f0 >> 6, row0 = f0 & 63;  // row0 in {0,16,32,48}
    bf16x8 a0 = *(const bf16x8*)&stb_c[f0];
    bf16x8 a1 = *(const bf16x8*)&stb_c[f0 + 8];
#pragma unroll
    for (int u = 0; u < 8; u++) {
      S0T[swz72(row0 + u, col)] = a0[u];
      S0T[swz72(row0 + 8 + u, col)] = a1[u];
    }
  }
  if (tid < DH) z0l[tid] = zbuf[((size_t)bh * NC + c) * 64 + tid];
  __syncthreads();

  // phase 1: P = Q K^T
  v4f zero = {0.f, 0.f, 0.f, 0.f};
  v4f pacc[4];
#pragma unroll
  for (int j = 0; j < 4; j++) pacc[j] = zero;
#pragma unroll
  for (int ks = 0; ks < 2; ks++) {
    bf16x8 aq = *(const bf16x8*)&Ql[swz72(wave * 16 + l16, ks * 32 + quad * 8)];
#pragma unroll
    for (int j = 0; j < 4; j++) {
      bf16x8 bk = *(const bf16x8*)&Kl[swz72(j * 16 + l16, ks * 32 + quad * 8)];
      pacc[j] = MFMA16(aq, bk, pacc[j]);
    }
  }
  float rs[4] = {0.f, 0.f, 0.f, 0.f};
#pragma unroll
  for (int j = 0; j < 4; j++) {
#pragma unroll
    for (int r = 0; r < 4; r++) {
      int t = wave * 16 + quad * 4 + r;
      int col = j * 16 + l16;
      float p = (col <= t) ? pacc[j][r] : 0.f;
      Pl[swz72(t, col)] = (bf16)p;
      rs[r] += p;
    }
  }
#pragma unroll
  for (int m = 1; m < 16; m <<= 1)
#pragma unroll
    for (int r = 0; r < 4; r++) rs[r] += __shfl_xor(rs[r], m, 64);
  if (l16 == 0)
#pragma unroll
    for (int r = 0; r < 4; r++) denl[wave * 16 + quad * 4 + r] = rs[r];
  __syncthreads();
  // den += q . z0 (wave-parallel: t = tid>>2 covers 0..63, p = 16-elem slice)
  {
    const int t = tid >> 2, p = tid & 3;
    bf16x8 qa = *(const bf16x8*)&Ql[swz72(t, p * 16)];
    bf16x8 qb2 = *(const bf16x8*)&Ql[swz72(t, p * 16 + 8)];
    float qz = 0.f;
#pragma unroll
    for (int u = 0; u < 8; u++)
      qz += (float)qa[u] * z0l[p * 16 + u] + (float)qb2[u] * z0l[p * 16 + 8 + u];
    qz += __shfl_xor(qz, 1, 64);
    qz += __shfl_xor(qz, 2, 64);
    if (p == 0) denl[t] += qz;
  }
  __syncthreads();

  // phase 2: num = P@V + Q@S0
  v4f nacc[4];
#pragma unroll
  for (int j = 0; j < 4; j++) nacc[j] = zero;
#pragma unroll
  for (int ks = 0; ks < 2; ks++) {
    bf16x8 ap = *(const bf16x8*)&Pl[swz72(wave * 16 + l16, ks * 32 + quad * 8)];
#pragma unroll
    for (int j = 0; j < 4; j++) {
      bf16x8 bv = *(const bf16x8*)&VT[swz72(j * 16 + l16, ks * 32 + quad * 8)];
      nacc[j] = MFMA16(ap, bv, nacc[j]);
    }
  }
#pragma unroll
  for (int ks = 0; ks < 2; ks++) {
    bf16x8 aq = *(const bf16x8*)&Ql[swz72(wave * 16 + l16, ks * 32 + quad * 8)];
#pragma unroll
    for (int j = 0; j < 4; j++) {
      bf16x8 bs = *(const bf16x8*)&S0T[swz72(j * 16 + l16, ks * 32 + quad * 8)];
      nacc[j] = MFMA16(aq, bs, nacc[j]);
    }
  }

  // epilogue: route output through Ql (dead now) for coalesced 16B stores
  __syncthreads();
  bf16* Ol = Ql;
#pragma unroll
  for (int j = 0; j < 4; j++) {
#pragma unroll
    for (int r = 0; r < 4; r++) {
      int t = wave * 16 + quad * 4 + r;
      int e = j * 16 + l16;
      Ol[swz72(t, e)] = (bf16)(nacc[j][r] / (denl[t] + EPS));
    }
  }
  __syncthreads();
  {
    const int orow = tid >> 2, oc0 = (tid & 3) * 16;
    bf16x8 q0 = *(const bf16x8*)&Ol[swz72(orow, oc0)];
    bf16x8 q1 = *(const bf16x8*)&Ol[swz72(orow, oc0 + 8)];
    bf16* dst = ao + gbase + (size_t)orow * D_ + oc0;
    *(bf16x8*)dst = q0;
    *(bf16x8*)(dst + 8) = q1;
  }
}

// ---------------------------------------------------------------------------
extern "C" void kernel_launch(void* const* d_in, const int* in_sizes, int n_in,
                              void* d_out, int out_size, void* d_ws, size_t ws_size,
                              hipStream_t stream) {
  const float* x  = (const float*)d_in[0];
  const float* sc = (const float*)d_in[1];
  const float* Wq = (const float*)d_in[2];
  const float* Wk = (const float*)d_in[3];
  const float* Wv = (const float*)d_in[4];
  const float* Wo = (const float*)d_in[5];
  float* out = (float*)d_out;

  const size_t MSZ = (size_t)B_ * S_ * D_;  // 16,777,216 elems
  const size_t WSZ = (size_t)D_ * D_;       // 1,048,576 elems
  bf16* xb = (bf16*)d_ws;
  bf16* qb = xb + MSZ;
  bf16* kb = qb + MSZ;
  bf16* vb = kb + MSZ;
  bf16* ao = vb + MSZ;
  bf16* wt = ao + MSZ;  // 4 transposed bf16 weight matrices [q|k|v|o]
  bf16* csum = wt + 4 * WSZ;            // bf16 chunk sums: BH*NC*4096 (32 MB)
  float* zbuf = (float*)(csum + (size_t)BH * NC * 4096);  // fp32 z: 1 MB
  bf16* stb = xb;  // bf16 prefix states reuse xb (dead after QKV GEMM);
                   // BH*NC*4096 = 16,777,216 elems — exact fit.

  cvt_f32_bf16<<<MSZ / (256 * 8), 256, 0, stream>>>(x, xb);
  transpose_w4<<<dim3(32, 32, 4), 256, 0, stream>>>(Wq, Wk, Wv, Wo, wt);

  // fused QKV GEMM: BT rows 0..3071 span wt[q|k|v]
  gemm_nt<<<dim3(128, 24), 256, 0, stream>>>(xb, wt, qb, kb, vb, nullptr);

  chunk_kv<<<dim3(NC, BH), 256, 0, stream>>>(kb, vb, csum, zbuf);
  state_prefix<<<dim3(BH, 65), 256, 0, stream>>>(sc, csum, zbuf, stb);
  attn_pass2<<<dim3(NC, BH), 256, 0, stream>>>(qb, kb, vb, zbuf, stb, ao);

  gemm_nt<<<dim3(128, 8), 256, 0, stream>>>(ao, wt + 3 * WSZ, nullptr, nullptr,
                                            nullptr, out);
}

// Round 10
// 390.692 us; speedup vs baseline: 1.1337x; 1.0108x over previous
//
#include <hip/hip_runtime.h>

#define B_ 4
#define S_ 4096
#define D_ 1024
#define H_ 16
#define DH 64
#define CHUNK 64
#define NC (S_ / CHUNK)   // 64 chunks
#define BH (B_ * H_)      // 64 (b,h) sequences
#define EPS 1e-6f

typedef __bf16 bf16;
typedef __bf16 bf16x8 __attribute__((ext_vector_type(8)));
typedef float v4f __attribute__((ext_vector_type(4)));

#define MFMA16(a, b, c) __builtin_amdgcn_mfma_f32_16x16x32_bf16(a, b, c, 0, 0, 0)

// async global->LDS, 16B per lane; LDS dest = wave-uniform base + lane*16
__device__ __forceinline__ void load_lds16(const bf16* g, bf16* l) {
  __builtin_amdgcn_global_load_lds(
      (const __attribute__((address_space(1))) unsigned int*)g,
      (__attribute__((address_space(3))) unsigned int*)l, 16, 0, 0);
}

// XOR-swizzled element offset for [R][72] bf16 LDS tiles (R<=64).
// (row,col) -> row*72 + ((col>>3 ^ row>>3)&7)*8 + (col&7).  Bijection; keeps
// 8-elem groups contiguous (b128-safe); kills transpose-scatter conflicts.
__device__ __forceinline__ int swz72(int row, int col) {
  return row * 72 + ((((col >> 3) ^ (row >> 3)) & 7) << 3) + (col & 7);
}

// ---------------------------------------------------------------------------
// fp32 -> bf16 convert (x): 8 elems/thread, vectorized.
// ---------------------------------------------------------------------------
__global__ __launch_bounds__(256) void cvt_f32_bf16(const float* __restrict__ in,
                                                    bf16* __restrict__ out) {
  const size_t i = ((size_t)blockIdx.x * 256 + threadIdx.x) * 8;
  float4 a = *(const float4*)(in + i);
  float4 b = *(const float4*)(in + i + 4);
  bf16x8 o;
  o[0] = (bf16)a.x; o[1] = (bf16)a.y; o[2] = (bf16)a.z; o[3] = (bf16)a.w;
  o[4] = (bf16)b.x; o[5] = (bf16)b.y; o[6] = (bf16)b.z; o[7] = (bf16)b.w;
  *(bf16x8*)(out + i) = o;
}

// ---------------------------------------------------------------------------
// Fused weight transpose + fp32->bf16 for all 4 weights (z selects matrix).
// ---------------------------------------------------------------------------
__global__ __launch_bounds__(256) void transpose_w4(
    const float* __restrict__ w0, const float* __restrict__ w1,
    const float* __restrict__ w2, const float* __restrict__ w3,
    bf16* __restrict__ out) {
  __shared__ float tile[32][33];
  const int z = blockIdx.z;
  const float* in = (z == 0) ? w0 : (z == 1) ? w1 : (z == 2) ? w2 : w3;
  bf16* o = out + (size_t)z * D_ * D_;
  const int bx = blockIdx.x * 32, by = blockIdx.y * 32;
  const int tx = threadIdx.x & 31, ty = threadIdx.x >> 5;  // 32 x 8
#pragma unroll
  for (int i = 0; i < 32; i += 8)
    tile[ty + i][tx] = in[(size_t)(by + ty + i) * D_ + bx + tx];
  __syncthreads();
#pragma unroll
  for (int i = 0; i < 32; i += 8)
    o[(size_t)(bx + ty + i) * D_ + by + tx] = (bf16)tile[tx][ty + i];
}

// ---------------------------------------------------------------------------
// NT GEMM, double-buffered global_load_lds prefetch, SWIZZLED LDS staging.
// (Round-0 proven kernel — unchanged.  256x256 8-phase variant: spilled, do
// not retry.  Fused middle scan: regressed (occupancy), do not retry.)
// ---------------------------------------------------------------------------
__global__ __launch_bounds__(256) void gemm_nt(const bf16* __restrict__ A,
                                               const bf16* __restrict__ BT,
                                               bf16* __restrict__ o0,
                                               bf16* __restrict__ o1,
                                               bf16* __restrict__ o2,
                                               float* __restrict__ of) {
  constexpr int TM = 128, BK = 32;
  constexpr int CLD = 132;
  __shared__ __align__(16) char smem[32768];
  float* Cl = (float*)smem;

  const int tid = threadIdx.x;
  const int wave = tid >> 6, lane = tid & 63;
  const int quad = lane >> 4, l16 = lane & 15;
  const int bm = blockIdx.x * TM;
  const int zz = blockIdx.y >> 3;
  const int colg = (blockIdx.y & 7) * 128;
  const int wm = (wave & 1) * 64, wn = (wave >> 1) * 64;
  const int act = (of == nullptr) && (zz < 2);
  bf16* ob = (zz == 0) ? o0 : (zz == 1) ? o1 : o2;

  const int srow = wave * 16 + (lane >> 2);
  const int sgrp = ((lane & 3) - ((lane >> 2) >> 1)) & 3;
  const bf16* gA0 = A + (size_t)(bm + srow) * D_ + sgrp * 8;
  const bf16* gA1 = gA0 + (size_t)64 * D_;
  const bf16* gB0 = BT + ((size_t)blockIdx.y * 128 + srow) * D_ + sgrp * 8;
  const bf16* gB1 = gB0 + (size_t)64 * D_;

  int offA[4], offB[4];
#pragma unroll
  for (int i = 0; i < 4; i++) {
    const int pg = (quad + (l16 >> 1)) & 3;
    offA[i] = (wm + i * 16 + l16) * BK + pg * 8;
    offB[i] = (wn + i * 16 + l16) * BK + pg * 8;
  }

  v4f zero = {0.f, 0.f, 0.f, 0.f};
  v4f acc[4][4];
#pragma unroll
  for (int i = 0; i < 4; i++)
#pragma unroll
    for (int j = 0; j < 4; j++) acc[i][j] = zero;

  auto stage = [&](int ks, int s) {
    bf16* As = (bf16*)(smem + s * 16384);
    bf16* Bs = As + 4096;
    const int ko = ks * BK;
    load_lds16(gA0 + ko, As + wave * 16 * BK);
    load_lds16(gA1 + ko, As + (64 + wave * 16) * BK);
    load_lds16(gB0 + ko, Bs + wave * 16 * BK);
    load_lds16(gB1 + ko, Bs + (64 + wave * 16) * BK);
  };
  auto compute = [&](int s) {
    const bf16* As = (const bf16*)(smem + s * 16384);
    const bf16* Bs = As + 4096;
    bf16x8 af[4], bfr[4];
#pragma unroll
    for (int i = 0; i < 4; i++) af[i] = *(const bf16x8*)&As[offA[i]];
#pragma unroll
    for (int j = 0; j < 4; j++) bfr[j] = *(const bf16x8*)&Bs[offB[j]];
#pragma unroll
    for (int i = 0; i < 4; i++)
#pragma unroll
      for (int j = 0; j < 4; j++) acc[i][j] = MFMA16(af[i], bfr[j], acc[i][j]);
  };

  constexpr int NK = D_ / BK;  // 32
  stage(0, 0);
  __syncthreads();
  for (int k = 0; k < NK; k += 2) {
    if (k + 1 < NK) stage(k + 1, 1);
    compute(0);
    __syncthreads();
    if (k + 2 < NK) stage(k + 2, 0);
    compute(1);
    __syncthreads();
  }

  const int lr = (wave & 1) * 16 + quad * 4;
  const int rrow = tid >> 3;
  const int rseg = (tid & 7) * 16;
  const int grow = bm + (rrow >> 4) * 64 + (rrow & 15);
#pragma unroll
  for (int i = 0; i < 4; i++) {
    __syncthreads();
#pragma unroll
    for (int j = 0; j < 4; j++) {
      const int col = wn + j * 16 + l16;
#pragma unroll
      for (int r = 0; r < 4; r++) {
        float x = acc[i][j][r];
        if (act) x = x > 0.f ? x + 1.f : __expf(x);
        Cl[(lr + r) * CLD + col] = x;
      }
    }
    __syncthreads();
    const float* src = &Cl[rrow * CLD + rseg];
    if (of) {
      float* dst = of + (size_t)(grow + i * 16) * D_ + colg + rseg;
#pragma unroll
      for (int u = 0; u < 4; u++)
        *(float4*)(dst + u * 4) = *(const float4*)(src + u * 4);
    } else {
      bf16x8 q0, q1;
#pragma unroll
      for (int u = 0; u < 8; u++) { q0[u] = (bf16)src[u]; q1[u] = (bf16)src[8 + u]; }
      bf16* dst = ob + (size_t)(grow + i * 16) * D_ + colg + rseg;
      *(bf16x8*)dst = q0;
      *(bf16x8*)(dst + 8) = q1;
    }
  }
}

// ---------------------------------------------------------------------------
// Pass 1: per-chunk KV outer-product sums (bf16 out) + k-sums (fp32), MFMA.
// KT/VT staged transposed with swz72.  grid (NC, BH) x 256.
// ---------------------------------------------------------------------------
__global__ __launch_bounds__(256) void chunk_kv(const bf16* __restrict__ kb,
                                                const bf16* __restrict__ vb,
                                                bf16* __restrict__ csum,
                                                float* __restrict__ zbuf) {
  __shared__ __align__(16) bf16 KT[DH * 72];  // KT[d][t] (swizzled)
  __shared__ __align__(16) bf16 VT[DH * 72];  // VT[e][t] (swizzled)
  const int tid = threadIdx.x;
  const int wave = tid >> 6, lane = tid & 63;
  const int quad = lane >> 4, l16 = lane & 15;
  const int c = blockIdx.x, bh = blockIdx.y;
  const int b = bh >> 4, h = bh & 15;
  const size_t gbase = ((size_t)(b * S_ + c * CHUNK)) * D_ + h * DH;
#pragma unroll
  for (int rep = 0; rep < 2; rep++) {
    int flat = tid + rep * 256;
    int r = flat >> 3, sg = (flat & 7) * 8;  // r = t, sg = d0
    bf16x8 kk = *(const bf16x8*)(kb + gbase + (size_t)r * D_ + sg);
    bf16x8 vv = *(const bf16x8*)(vb + gbase + (size_t)r * D_ + sg);
#pragma unroll
    for (int u = 0; u < 8; u++) {
      KT[swz72(sg + u, r)] = kk[u];
      VT[swz72(sg + u, r)] = vv[u];
    }
  }
  __syncthreads();

  v4f zero = {0.f, 0.f, 0.f, 0.f};
  v4f acc[4];
#pragma unroll
  for (int j = 0; j < 4; j++) acc[j] = zero;
#pragma unroll
  for (int ks = 0; ks < 2; ks++) {
    bf16x8 ak = *(const bf16x8*)&KT[swz72(wave * 16 + l16, ks * 32 + quad * 8)];
#pragma unroll
    for (int j = 0; j < 4; j++) {
      bf16x8 bv = *(const bf16x8*)&VT[swz72(j * 16 + l16, ks * 32 + quad * 8)];
      acc[j] = MFMA16(ak, bv, acc[j]);
    }
  }
  bf16* out = csum + ((size_t)bh * NC + c) * 4096;
#pragma unroll
  for (int j = 0; j < 4; j++)
#pragma unroll
    for (int r = 0; r < 4; r++)
      out[(wave * 16 + quad * 4 + r) * 64 + (j * 16 + l16)] = (bf16)acc[j][r];

  // z[d] = sum_t K[t][d]: 4 lanes per d, 16 elems each, shfl reduce (fp32)
  {
    const int d = tid >> 2, p = tid & 3;
    bf16x8 a0 = *(const bf16x8*)&KT[swz72(d, p * 16)];
    bf16x8 a1 = *(const bf16x8*)&KT[swz72(d, p * 16 + 8)];
    float zp = 0.f;
#pragma unroll
    for (int u = 0; u < 8; u++) zp += (float)a0[u] + (float)a1[u];
    zp += __shfl_xor(zp, 1, 64);
    zp += __shfl_xor(zp, 2, 64);
    if (p == 0) zbuf[((size_t)bh * NC + c) * 64 + d] = zp;
  }
}

// ---------------------------------------------------------------------------
// Exclusive prefix over chunks + state_cache init — PARALLEL SCAN.
// (Round-8 version — unchanged.)
// ---------------------------------------------------------------------------
__global__ __launch_bounds__(256) void state_prefix(const float* __restrict__ sc,
                                                    const bf16* __restrict__ csum,
                                                    float* __restrict__ zbuf,
                                                    bf16* __restrict__ stb) {
  const int bh = blockIdx.x;
  const int g = blockIdx.y;
  const int tid = threadIdx.x;
  const float* scb = sc + (size_t)bh * (DH + 1) * DH;
  if (g == 64) {
    if (tid < DH) {
      const int d = tid;
      float run = scb[4096 + d];
      float* p = zbuf + (size_t)bh * NC * 64 + d;
#pragma unroll 1
      for (int c = 0; c < NC; c += 4) {
        float t0 = p[(size_t)(c + 0) * 64];
        float t1 = p[(size_t)(c + 1) * 64];
        float t2 = p[(size_t)(c + 2) * 64];
        float t3 = p[(size_t)(c + 3) * 64];
        p[(size_t)(c + 0) * 64] = run; run += t0;
        p[(size_t)(c + 1) * 64] = run; run += t1;
        p[(size_t)(c + 2) * 64] = run; run += t2;
        p[(size_t)(c + 3) * 64] = run; run += t3;
      }
    }
    return;
  }
  __shared__ bf16 tile[NC][64];   // [c][x_loc] 8KB
  __shared__ bf16 otile[NC][64];  // output staging 8KB
  __shared__ float partial[4][64];
  const int x0 = g * 64;
  const bf16* base = csum + (size_t)bh * NC * 4096 + x0;
#pragma unroll
  for (int rep = 0; rep < 2; rep++) {
    int flat = tid + rep * 256;
    int c = flat >> 3, seg = (flat & 7) * 8;
    *(bf16x8*)&tile[c][seg] = *(const bf16x8*)(base + (size_t)c * 4096 + seg);
  }
  __syncthreads();
  const int x = tid & 63, cq = tid >> 6, c0 = cq * 16;
  float v[16];
  float s = 0.f;
#pragma unroll
  for (int k = 0; k < 16; k++) { v[k] = (float)tile[c0 + k][x]; s += v[k]; }
  partial[cq][x] = s;
  __syncthreads();
  float run = scb[x0 + x];
#pragma unroll
  for (int q = 0; q < 3; q++)
    if (q < cq) run += partial[q][x];
#pragma unroll
  for (int k = 0; k < 16; k++) { otile[c0 + k][x] = (bf16)run; run += v[k]; }
  __syncthreads();
  bf16* obase = stb + (size_t)bh * NC * 4096 + x0;
#pragma unroll
  for (int rep = 0; rep < 2; rep++) {
    int flat = tid + rep * 256;
    int c = flat >> 3, seg = (flat & 7) * 8;
    *(bf16x8*)(obase + (size_t)c * 4096 + seg) = *(const bf16x8*)&otile[c][seg];
  }
}

// ---------------------------------------------------------------------------
// Pass 2: P = mask(Q K^T) (incl. diagonal), num = P@V + Q@S0,
// den = rowsum(P) + Q.z0, out = num/(den+eps).  grid (NC, BH) x 256 (4 waves).
// Pl ALIASES Kl (dead after QK^T; one barrier guards the overwrite) ->
// LDS 46.6 -> 37.4 KB -> 4 blocks/CU (+33% occupancy).  Barrier audit:
// each wave's P rows land in and are read from its OWN 16-row band
// (same-wave LDS forwarding, no barrier); denl rowsum-writer and qz-adder
// for row t are the same wave (adder wave = t>>4 = writer wave).
// Output routed through Ql (dead after last MFMA) for coalesced stores.
// ---------------------------------------------------------------------------
__global__ __launch_bounds__(256) void attn_pass2(
    const bf16* __restrict__ qb, const bf16* __restrict__ kb,
    const bf16* __restrict__ vb, const float* __restrict__ zbuf,
    const bf16* __restrict__ stb, bf16* __restrict__ ao) {
  __shared__ __align__(16) bf16 Ql[CHUNK * 72];
  __shared__ __align__(16) bf16 Kl[CHUNK * 72];  // -> Pl after QK^T
  __shared__ __align__(16) bf16 VT[DH * 72];     // VT[e][j] = V[j][e]
  __shared__ __align__(16) bf16 S0T[DH * 72];    // S0T[e][d] = S0[d][e]
  __shared__ float denl[CHUNK];
  __shared__ float z0l[DH];
  const int tid = threadIdx.x;
  const int wave = tid >> 6, lane = tid & 63;
  const int quad = lane >> 4, l16 = lane & 15;
  const int c = blockIdx.x, bh = blockIdx.y;
  const int b = bh >> 4, h = bh & 15;
  const size_t gbase = ((size_t)(b * S_ + c * CHUNK)) * D_ + h * DH;

#pragma unroll
  for (int rep = 0; rep < 2; rep++) {
    int flat = tid + rep * 256;
    int r = flat >> 3, sg = (flat & 7) * 8;
    *(bf16x8*)&Ql[swz72(r, sg)] = *(const bf16x8*)(qb + gbase + (size_t)r * D_ + sg);
    *(bf16x8*)&Kl[swz72(r, sg)] = *(const bf16x8*)(kb + gbase + (size_t)r * D_ + sg);
    bf16x8 vv = *(const bf16x8*)(vb + gbase + (size_t)r * D_ + sg);
#pragma unroll
    for (int u = 0; u < 8; u++) VT[swz72(sg + u, r)] = vv[u];
  }
  // S0 staging from bf16 prefix states: thread handles 16 contiguous elems
  {
    const bf16* stb_c = stb + ((size_t)bh * NC + c) * 4096;
    const int f0 = tid * 16;
    const int col = f0 >> 6, row0 = f0 & 63;  // row0 in {0,16,32,48}
    bf16x8 a0 = *(const bf16x8*)&stb_c[f0];
    bf16x8 a1 = *(const bf16x8*)&stb_c[f0 + 8];
#pragma unroll
    for (int u = 0; u < 8; u++) {
      S0T[swz72(row0 + u, col)] = a0[u];
      S0T[swz72(row0 + 8 + u, col)] = a1[u];
    }
  }
  if (tid < DH) z0l[tid] = zbuf[((size_t)bh * NC + c) * 64 + tid];
  __syncthreads();  // (1) staging complete

  // phase 1: P = Q K^T
  v4f zero = {0.f, 0.f, 0.f, 0.f};
  v4f pacc[4];
#pragma unroll
  for (int j = 0; j < 4; j++) pacc[j] = zero;
  bf16x8 aq[2];
#pragma unroll
  for (int ks = 0; ks < 2; ks++) {
    aq[ks] = *(const bf16x8*)&Ql[swz72(wave * 16 + l16, ks * 32 + quad * 8)];
#pragma unroll
    for (int j = 0; j < 4; j++) {
      bf16x8 bk = *(const bf16x8*)&Kl[swz72(j * 16 + l16, ks * 32 + quad * 8)];
      pacc[j] = MFMA16(aq[ks], bk, pacc[j]);
    }
  }
  __syncthreads();  // (2) all waves done reading Kl -> safe to overwrite as Pl
  bf16* Pl = Kl;

  float rs[4] = {0.f, 0.f, 0.f, 0.f};
#pragma unroll
  for (int j = 0; j < 4; j++) {
#pragma unroll
    for (int r = 0; r < 4; r++) {
      int t = wave * 16 + quad * 4 + r;
      int col = j * 16 + l16;
      float p = (col <= t) ? pacc[j][r] : 0.f;
      Pl[swz72(t, col)] = (bf16)p;
      rs[r] += p;
    }
  }
#pragma unroll
  for (int m = 1; m < 16; m <<= 1)
#pragma unroll
    for (int r = 0; r < 4; r++) rs[r] += __shfl_xor(rs[r], m, 64);
  if (l16 == 0)
#pragma unroll
    for (int r = 0; r < 4; r++) denl[wave * 16 + quad * 4 + r] = rs[r];

  // den += q . z0 — adder wave (= (4t)>>6 = t>>4) == denl writer wave: no
  // barrier needed between init and add.
  {
    const int t = tid >> 2, p = tid & 3;
    bf16x8 qa = *(const bf16x8*)&Ql[swz72(t, p * 16)];
    bf16x8 qb2 = *(const bf16x8*)&Ql[swz72(t, p * 16 + 8)];
    float qz = 0.f;
#pragma unroll
    for (int u = 0; u < 8; u++)
      qz += (float)qa[u] * z0l[p * 16 + u] + (float)qb2[u] * z0l[p * 16 + 8 + u];
    qz += __shfl_xor(qz, 1, 64);
    qz += __shfl_xor(qz, 2, 64);
    if (p == 0) denl[t] += qz;
  }

  // phase 2: num = P@V + Q@S0.  P rows read are this wave's own band
  // (written above by this wave) — same-wave LDS forwarding, no barrier.
  v4f nacc[4];
#pragma unroll
  for (int j = 0; j < 4; j++) nacc[j] = zero;
#pragma unroll
  for (int ks = 0; ks < 2; ks++) {
    bf16x8 ap = *(const bf16x8*)&Pl[swz72(wave * 16 + l16, ks * 32 + quad * 8)];
#pragma unroll
    for (int j = 0; j < 4; j++) {
      bf16x8 bv = *(const bf16x8*)&VT[swz72(j * 16 + l16, ks * 32 + quad * 8)];
      nacc[j] = MFMA16(ap, bv, nacc[j]);
    }
  }
#pragma unroll
  for (int ks = 0; ks < 2; ks++) {
#pragma unroll
    for (int j = 0; j < 4; j++) {
      bf16x8 bs = *(const bf16x8*)&S0T[swz72(j * 16 + l16, ks * 32 + quad * 8)];
      nacc[j] = MFMA16(aq[ks], bs, nacc[j]);
    }
  }

  // epilogue: route output through Ql (dead now) for coalesced 16B stores
  __syncthreads();  // (3) Ql reads done everywhere; denl adds visible
  bf16* Ol = Ql;
#pragma unroll
  for (int j = 0; j < 4; j++) {
#pragma unroll
    for (int r = 0; r < 4; r++) {
      int t = wave * 16 + quad * 4 + r;
      int e = j * 16 + l16;
      Ol[swz72(t, e)] = (bf16)(nacc[j][r] / (denl[t] + EPS));
    }
  }
  __syncthreads();  // (4) Ol complete
  {
    const int orow = tid >> 2, oc0 = (tid & 3) * 16;
    bf16x8 q0 = *(const bf16x8*)&Ol[swz72(orow, oc0)];
    bf16x8 q1 = *(const bf16x8*)&Ol[swz72(orow, oc0 + 8)];
    bf16* dst = ao + gbase + (size_t)orow * D_ + oc0;
    *(bf16x8*)dst = q0;
    *(bf16x8*)(dst + 8) = q1;
  }
}

// ---------------------------------------------------------------------------
extern "C" void kernel_launch(void* const* d_in, const int* in_sizes, int n_in,
                              void* d_out, int out_size, void* d_ws, size_t ws_size,
                              hipStream_t stream) {
  const float* x  = (const float*)d_in[0];
  const float* sc = (const float*)d_in[1];
  const float* Wq = (const float*)d_in[2];
  const float* Wk = (const float*)d_in[3];
  const float* Wv = (const float*)d_in[4];
  const float* Wo = (const float*)d_in[5];
  float* out = (float*)d_out;

  const size_t MSZ = (size_t)B_ * S_ * D_;  // 16,777,216 elems
  const size_t WSZ = (size_t)D_ * D_;       // 1,048,576 elems
  bf16* xb = (bf16*)d_ws;
  bf16* qb = xb + MSZ;
  bf16* kb = qb + MSZ;
  bf16* vb = kb + MSZ;
  bf16* ao = vb + MSZ;
  bf16* wt = ao + MSZ;  // 4 transposed bf16 weight matrices [q|k|v|o]
  bf16* csum = wt + 4 * WSZ;            // bf16 chunk sums: BH*NC*4096 (32 MB)
  float* zbuf = (float*)(csum + (size_t)BH * NC * 4096);  // fp32 z: 1 MB
  bf16* stb = xb;  // bf16 prefix states reuse xb (dead after QKV GEMM);
                   // BH*NC*4096 = 16,777,216 elems — exact fit.

  cvt_f32_bf16<<<MSZ / (256 * 8), 256, 0, stream>>>(x, xb);
  transpose_w4<<<dim3(32, 32, 4), 256, 0, stream>>>(Wq, Wk, Wv, Wo, wt);

  // fused QKV GEMM: BT rows 0..3071 span wt[q|k|v]
  gemm_nt<<<dim3(128, 24), 256, 0, stream>>>(xb, wt, qb, kb, vb, nullptr);

  chunk_kv<<<dim3(NC, BH), 256, 0, stream>>>(kb, vb, csum, zbuf);
  state_prefix<<<dim3(BH, 65), 256, 0, stream>>>(sc, csum, zbuf, stb);
  attn_pass2<<<dim3(NC, BH), 256, 0, stream>>>(qb, kb, vb, zbuf, stb, ao);

  gemm_nt<<<dim3(128, 8), 256, 0, stream>>>(ao, wt + 3 * WSZ, nullptr, nullptr,
                                            nullptr, out);
}